// Round 4
// baseline (333.835 us; speedup 1.0000x reference)
//
#include <hip/hip_runtime.h>
#include <math.h>

// glp_rotation_pool: rotate (B,C,H,W,A) slices by -(360/A)*(a%K) degrees
// (nearest-neighbor, zero fill) then max-pool groups of K along A.
// Shapes hardcoded per setup_inputs(): B=8,C=16,H=128,W=128,A=24,K=4 -> G=6.
//
// R7 == R6 resubmitted (R6 bench died with an infra error, no measurement).
// R6 vs R5 (kernel 130us; latency-bound: nothing saturated — HBM 18%,
// L2 ~31%, VALU 24% — with only 2 blocks/CU of lockstepped phases):
//  - retile 32x16 -> 16x16. Square tiles minimize rotated-window area:
//    windows k0 16x16, k1 20x20, k2 22x22, k3 23x23; records/px 7.0->6.5
//    (line traffic slightly down) and LDS 53.7KB -> 24.3KB -> 6 blocks/CU
//    (24 waves: 3x the independent pipelines; 4-wave barriers are cheap).
//  - staging/vmcnt/barrier structure carried verbatim from R5: async
//    global_load_lds (size=4, lane stride 16B picks channel k), double
//    buffer (buf0: k0,k2; buf1: k1,k3), counted vmcnt (never 0 mid-loop),
//    dup-row trick keeps per-wave issue counts compile-time uniform.
//  - defensive s_waitcnt lgkmcnt(0) after each gather before s_barrier
//    (wave's ds_reads complete before others' stage writes can land).

// Replicate reference f32 arithmetic exactly: no FMA contraction in this TU.
#pragma clang fp contract(off)

#define HH 128
#define WW 128
#define AA 24
#define GG 6
#define TS 16
#define NWAVE 4

#define GLDS(gp, lp)                                       \
  __builtin_amdgcn_global_load_lds(                        \
      (const __attribute__((address_space(1))) void*)(gp), \
      (__attribute__((address_space(3))) void*)(lp), 4, 0, 0)

template <int K>
__device__ __forceinline__ void ktrig(float& cth, float& sth) {
  // theta = deg2rad(-15*K) in f32 exactly like the reference; correctly-
  // rounded f32 trig via double eval (constant-folds per K).
  float tdeg = -15.0f * (float)K;
  float theta = tdeg * 0.017453292519943295f;
  cth = (float)cos((double)theta);
  sth = (float)sin((double)theta);
}

// Window origin for k: rint(min corner xs/ys), clamped so the fixed WKxHK
// window lies fully inside the image. Monotone f32 ops => corner min bounds
// all interior pixels. W = ceil(span)+1 with span = 15*(|c|+|s|):
// k1 18.37->20, k2 20.49->22, k3 21.21->23 (margins >= 0.5 px >> f32 eps);
// k0 is the exact identity (span 15, W 16, no rounding error).
template <int K, int WK, int HK>
__device__ __forceinline__ void window_k(float xga, float xgb, float yga,
                                         float ygb, int& bx0, int& by0) {
  float cth, sth;
  ktrig<K>(cth, sth);
  float xs00 = cth * xga + sth * yga + 63.5f;
  float xs01 = cth * xga + sth * ygb + 63.5f;
  float xs10 = cth * xgb + sth * yga + 63.5f;
  float xs11 = cth * xgb + sth * ygb + 63.5f;
  float ys00 = (-sth) * xga + cth * yga + 63.5f;
  float ys01 = (-sth) * xga + cth * ygb + 63.5f;
  float ys10 = (-sth) * xgb + cth * yga + 63.5f;
  float ys11 = (-sth) * xgb + cth * ygb + 63.5f;
  float minxs = fminf(fminf(xs00, xs01), fminf(xs10, xs11));
  float minys = fminf(fminf(ys00, ys01), fminf(ys10, ys11));
  bx0 = min(max((int)rintf(minxs), 0), WW - WK);
  by0 = min(max((int)rintf(minys), 0), HH - HK);
}

// Stage channel-K plane of the WKxHK window into LDS via async
// global_load_lds. Per row: LR = WK*6 floats; lane q <- global float 4q+K.
// Per-wave issue count is compile-time uniform: NJ*(NFULL + (REM?1:0)).
template <int K, int WK, int HK>
__device__ __forceinline__ void stage_k(const float* sbase, float* lplane,
                                        int bx0, int by0, int wave, int lane) {
  constexpr int LR = WK * GG;
  constexpr int NFULL = LR >> 6;
  constexpr int REM = LR & 63;
  constexpr int NJ = (HK + NWAVE - 1) / NWAVE;
#pragma unroll
  for (int j = 0; j < NJ; ++j) {
    int dy = wave + NWAVE * j;
    dy = dy < HK ? dy : HK - 1;  // dup rows keep counts uniform (same data)
    const float* row = sbase + ((by0 + dy) * WW + bx0) * AA + K;
    float* lrow = lplane + dy * LR;
#pragma unroll
    for (int c = 0; c < NFULL; ++c) {
      GLDS(row + 4 * (64 * c + lane), lrow + 64 * c);
    }
    if (REM && lane < REM) {  // exec!=0 always -> vmcnt still +1 per wave
      GLDS(row + 4 * (64 * NFULL + lane), lrow + 64 * NFULL);
    }
  }
}

template <int K, int WK, int HK>
__device__ __forceinline__ void gather_k(const float* lplane, int bx0, int by0,
                                         float xg, float yg, float* r) {
  float cth, sth;
  ktrig<K>(cth, sth);
  float xs = cth * xg + sth * yg + 63.5f;  // no fma (contract off)
  float ys = (-sth) * xg + cth * yg + 63.5f;
  int xi = (int)rintf(xs);  // round-half-even == jnp.round
  int yi = (int)rintf(ys);
  bool valid = ((unsigned)xi < (unsigned)WW) & ((unsigned)yi < (unsigned)HH);
  // valid => xi-bx0 in [0,WK) proven; clamp only guards invalid lanes' LDS
  // addressing.
  int dxr = min(max(xi - bx0, 0), WK - 1);
  int dyr = min(max(yi - by0, 0), HK - 1);
  const float2* lp = (const float2*)(lplane + dyr * (WK * GG) + dxr * GG);
  float2 v01 = lp[0];
  float2 v23 = lp[1];
  float2 v45 = lp[2];
  r[0] = fmaxf(r[0], valid ? v01.x : 0.0f);  // zero fill joins the max
  r[1] = fmaxf(r[1], valid ? v01.y : 0.0f);
  r[2] = fmaxf(r[2], valid ? v23.x : 0.0f);
  r[3] = fmaxf(r[3], valid ? v23.y : 0.0f);
  r[4] = fmaxf(r[4], valid ? v45.x : 0.0f);
  r[5] = fmaxf(r[5], valid ? v45.y : 0.0f);
}

__global__ __launch_bounds__(256, 6) void glp_rotation_pool_kernel(
    const float* __restrict__ img, float* __restrict__ out) {
  __shared__ __align__(16) float buf0[2904];  // max(16*16, 22*22) * 6
  __shared__ __align__(16) float buf1[3174];  // max(20*20, 23*23) * 6

  // 8192 blocks = 128 slices x 64 tiles; xcd = blk&7 round-robin heuristic:
  // each XCD works 16 slices, tiles of one slice together in its L2.
  int blk = blockIdx.x;
  int xcd = blk & 7;
  int i = blk >> 3;                // 0..1023
  int bc = (xcd << 4) | (i >> 6);  // slice 0..127
  int tile = i & 63;
  int ty = (tile >> 3) << 4;  // 0..112 step 16
  int tx = (tile & 7) << 4;

  int tid = threadIdx.x;  // 0..255
  int px = tid & 15;
  int py = tid >> 4;  // 0..15
  int wave = tid >> 6;
  int lane = tid & 63;

  const float* sbase = img + (size_t)bc * (HH * WW * AA);

  float xg = (float)(tx + px) - 63.5f;
  float yg = (float)(ty + py) - 63.5f;
  float xga = (float)tx - 63.5f, xgb = (float)(tx + TS - 1) - 63.5f;
  float yga = (float)ty - 63.5f, ygb = (float)(ty + TS - 1) - 63.5f;

  int bx0_0, by0_0, bx0_1, by0_1, bx0_2, by0_2, bx0_3, by0_3;
  window_k<0, 16, 16>(xga, xgb, yga, ygb, bx0_0, by0_0);
  window_k<1, 20, 20>(xga, xgb, yga, ygb, bx0_1, by0_1);
  window_k<2, 22, 22>(xga, xgb, yga, ygb, bx0_2, by0_2);
  window_k<3, 23, 23>(xga, xgb, yga, ygb, bx0_3, by0_3);

  float r[6] = {-INFINITY, -INFINITY, -INFINITY,
                -INFINITY, -INFINITY, -INFINITY};

  // Pipeline: per-wave gl_lds issue counts {8,10,18,18} for k={0,1,2,3}.
  // Counted vmcnt leaves the next k's loads in flight (in-order completion).
  stage_k<0, 16, 16>(sbase, buf0, bx0_0, by0_0, wave, lane);  // +8
  stage_k<1, 20, 20>(sbase, buf1, bx0_1, by0_1, wave, lane);  // +10 (out 18)
  asm volatile("s_waitcnt vmcnt(10)" ::: "memory");           // k0 landed
  __builtin_amdgcn_sched_barrier(0);
  __builtin_amdgcn_s_barrier();
  __builtin_amdgcn_sched_barrier(0);
  gather_k<0, 16, 16>(buf0, bx0_0, by0_0, xg, yg, r);
  asm volatile("s_waitcnt lgkmcnt(0)" ::: "memory");  // my buf0 reads done
  __builtin_amdgcn_sched_barrier(0);
  __builtin_amdgcn_s_barrier();  // all waves done reading buf0
  __builtin_amdgcn_sched_barrier(0);
  stage_k<2, 22, 22>(sbase, buf0, bx0_2, by0_2, wave, lane);  // +18 (out 28)
  asm volatile("s_waitcnt vmcnt(18)" ::: "memory");           // k1 landed
  __builtin_amdgcn_sched_barrier(0);
  __builtin_amdgcn_s_barrier();
  __builtin_amdgcn_sched_barrier(0);
  gather_k<1, 20, 20>(buf1, bx0_1, by0_1, xg, yg, r);
  asm volatile("s_waitcnt lgkmcnt(0)" ::: "memory");  // my buf1 reads done
  __builtin_amdgcn_sched_barrier(0);
  __builtin_amdgcn_s_barrier();  // all waves done reading buf1
  __builtin_amdgcn_sched_barrier(0);
  stage_k<3, 23, 23>(sbase, buf1, bx0_3, by0_3, wave, lane);  // +18 (out 36)
  asm volatile("s_waitcnt vmcnt(18)" ::: "memory");           // k2 landed
  __builtin_amdgcn_sched_barrier(0);
  __builtin_amdgcn_s_barrier();
  __builtin_amdgcn_sched_barrier(0);
  gather_k<2, 22, 22>(buf0, bx0_2, by0_2, xg, yg, r);
  asm volatile("s_waitcnt vmcnt(0) lgkmcnt(0)" ::: "memory");  // k3 landed
  __builtin_amdgcn_sched_barrier(0);
  __builtin_amdgcn_s_barrier();
  __builtin_amdgcn_sched_barrier(0);
  gather_k<3, 23, 23>(buf1, bx0_3, by0_3, xg, yg, r);

  // out float index = ((bc*H*W + y*W + x)*G); 24B per pixel, 8B-aligned.
  size_t opix =
      ((size_t)bc * (HH * WW) + (size_t)(ty + py) * WW + (tx + px)) * GG;
  float2* op = (float2*)&out[opix];
  op[0] = make_float2(r[0], r[1]);
  op[1] = make_float2(r[2], r[3]);
  op[2] = make_float2(r[4], r[5]);
}

extern "C" void kernel_launch(void* const* d_in, const int* in_sizes, int n_in,
                              void* d_out, int out_size, void* d_ws,
                              size_t ws_size, hipStream_t stream) {
  const float* img = (const float*)d_in[0];
  float* out = (float*)d_out;
  // 128 slices * 64 tiles = 8192 blocks of 256 threads
  dim3 grid(128 * 64);
  dim3 block(256);
  glp_rotation_pool_kernel<<<grid, block, 0, stream>>>(img, out);
}